// Round 3
// baseline (1085.050 us; speedup 1.0000x reference)
//
#include <hip/hip_runtime.h>
#include <stdint.h>
#include <math.h>

#define IN_DIM 512
#define HID    256
#define OUTD   128
#define LN_EPS 1e-5f

typedef unsigned short u16;
typedef unsigned int   u32;
typedef short short8 __attribute__((ext_vector_type(8)));
typedef float f32x4  __attribute__((ext_vector_type(4)));

__device__ __forceinline__ float bf2f(u32 h) {
  union { u32 u; float f; } c; c.u = h << 16; return c.f;
}
__device__ __forceinline__ u16 f2bf(float f) {
  union { float f; u32 u; } c; c.f = f;
  u32 u = c.u;
  return (u16)((u + 0x7FFFu + ((u >> 16) & 1u)) >> 16);  // RNE
}

__device__ __forceinline__ void gload_lds16(const void* g, void* l) {
  __builtin_amdgcn_global_load_lds((const __attribute__((address_space(1))) void*)g,
                                   (__attribute__((address_space(3))) void*)l, 16, 0, 0);
}

// ---------------- fused prep: x->bf16, 8 weight transposes, 2 bias concats ----
// regions on a flat thread id (saves ~10 dispatches vs separate kernels)
__global__ void k_prep(const float* __restrict__ x, u16* __restrict__ x_bf, int n4,
                       const float* __restrict__ Wq1, const float* __restrict__ Wk1,
                       const float* __restrict__ Wv1, const float* __restrict__ Ws1,
                       const float* __restrict__ Wq2, const float* __restrict__ Wk2,
                       const float* __restrict__ Wv2, const float* __restrict__ Ws2,
                       u16* __restrict__ Wt1, u16* __restrict__ Wt2,
                       const float* __restrict__ bq1, const float* __restrict__ bk1,
                       const float* __restrict__ bv1, const float* __restrict__ bs1,
                       const float* __restrict__ bq2, const float* __restrict__ bk2,
                       const float* __restrict__ bv2, const float* __restrict__ bs2,
                       float* __restrict__ bc1, float* __restrict__ bc2) {
  const int W1SZ = 4 * HID * IN_DIM;   // 524288, per-mat 2^17
  const int W2SZ = 4 * OUTD * HID;     // 131072, per-mat 2^15
  int id = blockIdx.x * blockDim.x + threadIdx.x;
  if (id < n4) {
    const float4 v = ((const float4*)x)[id];
    ushort4 o;
    o.x = f2bf(v.x); o.y = f2bf(v.y); o.z = f2bf(v.z); o.w = f2bf(v.w);
    ((ushort4*)x_bf)[id] = o;
    return;
  }
  id -= n4;
  if (id < W1SZ) {  // out[mat][n*512+k] = in[k*256+n], K=512 Nw=256
    int mat = id >> 17, r = id & 131071;
    int n = r >> 9, k = r & 511;
    const float* src = (mat == 0) ? Wq1 : (mat == 1) ? Wk1 : (mat == 2) ? Wv1 : Ws1;
    Wt1[id] = f2bf(src[k * HID + n]);
    return;
  }
  id -= W1SZ;
  if (id < W2SZ) {  // K=256 Nw=128
    int mat = id >> 15, r = id & 32767;
    int n = r >> 8, k = r & 255;
    const float* src = (mat == 0) ? Wq2 : (mat == 1) ? Wk2 : (mat == 2) ? Wv2 : Ws2;
    Wt2[id] = f2bf(src[k * OUTD + n]);
    return;
  }
  id -= W2SZ;
  if (id < 4 * HID) {
    const float* s = (id < HID) ? bq1 : (id < 2 * HID) ? bk1 : (id < 3 * HID) ? bv1 : bs1;
    bc1[id] = s[id & (HID - 1)];
    return;
  }
  id -= 4 * HID;
  if (id < 4 * OUTD) {
    const float* s = (id < OUTD) ? bq2 : (id < 2 * OUTD) ? bk2 : (id < 3 * OUTD) ? bv2 : bs2;
    bc2[id] = s[id & (OUTD - 1)];
  }
}

// ---------------- edge sort (counting sort by dst) ----------------
__global__ void k_hist(const int* __restrict__ dst, int* __restrict__ deg, int E) {
  int e = blockIdx.x * blockDim.x + threadIdx.x;
  if (e < E) atomicAdd(&deg[dst[e]], 1);
}

__global__ void k_block_sum(const int* __restrict__ deg, int* __restrict__ bsum, int n) {
  __shared__ int sm[256];
  int i = blockIdx.x * 256 + threadIdx.x;
  sm[threadIdx.x] = (i < n) ? deg[i] : 0;
  __syncthreads();
  for (int off = 128; off > 0; off >>= 1) {
    if (threadIdx.x < off) sm[threadIdx.x] += sm[threadIdx.x + off];
    __syncthreads();
  }
  if (threadIdx.x == 0) bsum[blockIdx.x] = sm[0];
}

__global__ void k_scan_bsum(const int* __restrict__ bsum, int* __restrict__ boff, int nb) {
  __shared__ int sm[256];
  int t = threadIdx.x;
  int v = (t < nb) ? bsum[t] : 0;
  sm[t] = v;
  __syncthreads();
  for (int off = 1; off < 256; off <<= 1) {
    int tmp = (t >= off) ? sm[t - off] : 0;
    __syncthreads();
    sm[t] += tmp;
    __syncthreads();
  }
  if (t < nb) boff[t] = sm[t] - v;  // exclusive
}

__global__ void k_scan_final(const int* __restrict__ deg, const int* __restrict__ boff,
                             int* __restrict__ offsets, int* __restrict__ cur,
                             int n, int total) {
  __shared__ int sm[256];
  int t = threadIdx.x;
  int i = blockIdx.x * 256 + t;
  int v = (i < n) ? deg[i] : 0;
  sm[t] = v;
  __syncthreads();
  for (int off = 1; off < 256; off <<= 1) {
    int tmp = (t >= off) ? sm[t - off] : 0;
    __syncthreads();
    sm[t] += tmp;
    __syncthreads();
  }
  if (i < n) {
    int o = boff[blockIdx.x] + sm[t] - v;
    offsets[i] = o;
    cur[i] = o;
  }
  if (i == 0) offsets[n] = total;
}

__global__ void k_scatter(const int* __restrict__ src, const int* __restrict__ dst,
                          int* __restrict__ cursor, int* __restrict__ ssrc, int E) {
  int e = blockIdx.x * blockDim.x + threadIdx.x;
  if (e >= E) return;
  int d = dst[e];
  int pos = atomicAdd(&cursor[d], 1);
  ssrc[pos] = src[e];
}

// ---------------- bf16 NT GEMM (m97 structure) ----------------
__global__ __launch_bounds__(256) void k_gemm_bf16_nt(
    const u16* __restrict__ A, const u16* __restrict__ Bt, const float* __restrict__ bias,
    u16* __restrict__ C, int M, int K, int Nt) {
  __shared__ __align__(16) u16 As[128 * 32];
  __shared__ __align__(16) u16 Bs[128 * 32];
  const int tid = threadIdx.x;
  const int bm0 = blockIdx.x * 128;
  const int bn0 = blockIdx.y * 128;
  const int wave = tid >> 6, lane = tid & 63;
  const int q = lane >> 4, r16 = lane & 15;
  const int wm = (wave >> 1) * 64, wn = (wave & 1) * 64;

  f32x4 acc[4][4];
#pragma unroll
  for (int i = 0; i < 4; i++)
#pragma unroll
    for (int j = 0; j < 4; j++) acc[i][j] = (f32x4){0.f, 0.f, 0.f, 0.f};

  const int r0 = tid >> 2;
  const int c0 = (tid & 3) * 8;

  for (int kt = 0; kt < K; kt += 32) {
#pragma unroll
    for (int h = 0; h < 2; ++h) {
      int row = r0 + h * 64;
      gload_lds16(A + (size_t)(bm0 + row) * K + kt + c0, &As[row * 32 + c0]);
      gload_lds16(Bt + (size_t)(bn0 + row) * K + kt + c0, &Bs[row * 32 + c0]);
    }
    __syncthreads();
    short8 af[4], bfr[4];
#pragma unroll
    for (int i = 0; i < 4; i++) af[i] = *(const short8*)(&As[(wm + i * 16 + r16) * 32 + q * 8]);
#pragma unroll
    for (int j = 0; j < 4; j++) bfr[j] = *(const short8*)(&Bs[(wn + j * 16 + r16) * 32 + q * 8]);
#pragma unroll
    for (int i = 0; i < 4; i++)
#pragma unroll
      for (int j = 0; j < 4; j++)
        acc[i][j] = __builtin_amdgcn_mfma_f32_16x16x32_bf16(af[i], bfr[j], acc[i][j], 0, 0, 0);
    __syncthreads();
  }

#pragma unroll
  for (int i = 0; i < 4; i++) {
#pragma unroll
    for (int r = 0; r < 4; r++) {
      int grow = bm0 + wm + i * 16 + q * 4 + r;
      if (grow >= M) continue;
      size_t rbase = (size_t)grow * Nt;
#pragma unroll
      for (int j = 0; j < 4; j++) {
        int gcol = bn0 + wn + j * 16 + r16;
        float v = acc[i][j][r] + bias[gcol];
        C[rbase + gcol] = f2bf(v);
      }
    }
  }
}

// ---------------- conv: subwave-per-edge online softmax + fused global stats --
// SUBW = H/8 lanes per edge; each lane holds 8 elems (one uint4 load).
// EPW = 64/SUBW edges per wave step; U steps unrolled -> EPW*U edges in flight.
template <int H, bool OUT_BF16>
__global__ __launch_bounds__(256) void k_conv(
    const u16* __restrict__ qkvs, const int* __restrict__ offsets,
    const int* __restrict__ ssrc, u16* __restrict__ out_bf,
    float* __restrict__ out_f, int n, float scale, double* __restrict__ st) {
  constexpr int SUBW = H / 8;        // 32 (H=256) or 16 (H=128)
  constexpr int EPW = 64 / SUBW;     // 2 or 4
  constexpr int U = (H == 256) ? 4 : 2;  // edges in flight: 8

  const int wave = threadIdx.x >> 6;
  const int lane = threadIdx.x & 63;
  const int sub = lane & (SUBW - 1);
  const int subid = lane >> ((H == 256) ? 5 : 4);
  const int gw = blockIdx.x * 4 + wave;  // one wave per dst node

  float m = -INFINITY, l = 0.f;
  float agg[8];
#pragma unroll
  for (int w = 0; w < 8; w++) agg[w] = 0.f;
  float r[8];
#pragma unroll
  for (int w = 0; w < 8; w++) r[w] = 0.f;
  bool live = gw < n;
  int beg = 0, end = 0;

  if (live) {
    const u16* base = qkvs + (size_t)gw * (4 * H);
    float qf[8];
    {
      uint4 qv = *(const uint4*)(base + sub * 8);
      const u32 qa[4] = {qv.x, qv.y, qv.z, qv.w};
#pragma unroll
      for (int w = 0; w < 4; w++) {
        qf[2 * w] = bf2f(qa[w] & 0xffffu);
        qf[2 * w + 1] = bf2f(qa[w] >> 16);
      }
    }
    beg = offsets[gw]; end = offsets[gw + 1];

    int i = beg;
    for (; i + EPW * U <= end; i += EPW * U) {
      uint4 kq[U], vq[U];
      const u16* kp[U];
#pragma unroll
      for (int u = 0; u < U; u++) {
        int s = ssrc[i + u * EPW + subid];
        kp[u] = qkvs + (size_t)s * (4 * H) + H;
      }
#pragma unroll
      for (int u = 0; u < U; u++) kq[u] = *(const uint4*)(kp[u] + sub * 8);
#pragma unroll
      for (int u = 0; u < U; u++) vq[u] = *(const uint4*)(kp[u] + H + sub * 8);
      float d[U];
#pragma unroll
      for (int u = 0; u < U; u++) {
        const u32 ka[4] = {kq[u].x, kq[u].y, kq[u].z, kq[u].w};
        float dd = 0.f;
#pragma unroll
        for (int w = 0; w < 4; w++) {
          dd += qf[2 * w] * bf2f(ka[w] & 0xffffu);
          dd += qf[2 * w + 1] * bf2f(ka[w] >> 16);
        }
        d[u] = dd;
      }
#pragma unroll
      for (int off = SUBW / 2; off > 0; off >>= 1)
#pragma unroll
        for (int u = 0; u < U; u++) d[u] += __shfl_xor(d[u], off, 64);
      float cm = -INFINITY;
#pragma unroll
      for (int u = 0; u < U; u++) { d[u] *= scale; cm = fmaxf(cm, d[u]); }
      float nm = fmaxf(m, cm);
      float sc = __expf(m - nm);  // m=-inf first iter -> 0
      float p[U];
      float ps = 0.f;
#pragma unroll
      for (int u = 0; u < U; u++) { p[u] = __expf(d[u] - nm); ps += p[u]; }
      m = nm;
      l = l * sc + ps;
#pragma unroll
      for (int w = 0; w < 8; w++) {
        float a = agg[w] * sc;
#pragma unroll
        for (int u = 0; u < U; u++) {
          const u32 vv = ((const u32*)&vq[u])[w >> 1];
          float vf = bf2f((w & 1) ? (vv >> 16) : (vv & 0xffffu));
          a += p[u] * vf;
        }
        agg[w] = a;
      }
    }
    // tail: EPW edges per step, predicated per-subwave
    for (; i < end; i += EPW) {
      int e = i + subid;
      bool act = e < end;
      int s = act ? ssrc[e] : ssrc[i];
      const u16* kp = qkvs + (size_t)s * (4 * H) + H;
      uint4 kq = *(const uint4*)(kp + sub * 8);
      uint4 vq = *(const uint4*)(kp + H + sub * 8);
      const u32 ka[4] = {kq.x, kq.y, kq.z, kq.w};
      float d = 0.f;
#pragma unroll
      for (int w = 0; w < 4; w++) {
        d += qf[2 * w] * bf2f(ka[w] & 0xffffu);
        d += qf[2 * w + 1] * bf2f(ka[w] >> 16);
      }
#pragma unroll
      for (int off = SUBW / 2; off > 0; off >>= 1) d += __shfl_xor(d, off, 64);
      d = act ? d * scale : -INFINITY;
      float nm = fmaxf(m, d);
      bool dead = (nm == -INFINITY);
      float sc = dead ? 1.f : __expf(m - nm);
      float p = dead ? 0.f : __expf(d - nm);
      m = nm;
      l = l * sc + p;
#pragma unroll
      for (int w = 0; w < 8; w++) {
        const u32 vv = ((const u32*)&vq)[w >> 1];
        float vf = bf2f((w & 1) ? (vv >> 16) : (vv & 0xffffu));
        agg[w] = agg[w] * sc + p * vf;
      }
    }

    // merge subwave states (1 step for SUBW=32, 2 for SUBW=16)
#pragma unroll
    for (int off = SUBW; off < 64; off <<= 1) {
      float mo = __shfl_xor(m, off, 64);
      float lo = __shfl_xor(l, off, 64);
      float M = fmaxf(m, mo);
      float sa = (M == -INFINITY) ? 0.f : __expf(m - M);
      float sb = (M == -INFINITY) ? 0.f : __expf(mo - M);
      l = l * sa + lo * sb;
#pragma unroll
      for (int w = 0; w < 8; w++) {
        float ao = __shfl_xor(agg[w], off, 64);
        agg[w] = agg[w] * sa + ao * sb;
      }
      m = M;
    }

    // skip connection + output (subid==0 lanes own the result)
    float sf[8];
    {
      uint4 sv = *(const uint4*)(base + 3 * H + sub * 8);
      const u32 sa[4] = {sv.x, sv.y, sv.z, sv.w};
#pragma unroll
      for (int w = 0; w < 4; w++) {
        sf[2 * w] = bf2f(sa[w] & 0xffffu);
        sf[2 * w + 1] = bf2f(sa[w] >> 16);
      }
    }
    float inv = (end > beg) ? 1.f / l : 0.f;
#pragma unroll
    for (int w = 0; w < 8; w++) r[w] = agg[w] * inv + sf[w];
    if (subid == 0) {
      if (OUT_BF16) {
        uint4 o;
        u32* op = (u32*)&o;
#pragma unroll
        for (int w = 0; w < 4; w++)
          op[w] = (u32)f2bf(r[2 * w]) | ((u32)f2bf(r[2 * w + 1]) << 16);
        *(uint4*)(out_bf + (size_t)gw * H + sub * 8) = o;
      } else {
        float4 o0 = {r[0], r[1], r[2], r[3]};
        float4 o1 = {r[4], r[5], r[6], r[7]};
        *(float4*)(out_f + (size_t)gw * H + sub * 8) = o0;
        *(float4*)(out_f + (size_t)gw * H + sub * 8 + 4) = o1;
      }
    }
  }

  // fused global stats: sum & sum-of-squares of this block's outputs
  float s = 0.f, s2 = 0.f;
  if (live && subid == 0) {
#pragma unroll
    for (int w = 0; w < 8; w++) { s += r[w]; s2 += r[w] * r[w]; }
  }
#pragma unroll
  for (int off = 32; off > 0; off >>= 1) {
    s += __shfl_xor(s, off, 64);
    s2 += __shfl_xor(s2, off, 64);
  }
  __shared__ float bs_[8];
  if (lane == 0) { bs_[wave * 2] = s; bs_[wave * 2 + 1] = s2; }
  __syncthreads();
  if (wave == 0 && lane == 0) {
    float ts = bs_[0] + bs_[2] + bs_[4] + bs_[6];
    float ts2 = bs_[1] + bs_[3] + bs_[5] + bs_[7];
    atomicAdd(&st[0], (double)ts);
    atomicAdd(&st[1], (double)ts2);
  }
}

// ---------------- layernorm finalize + apply ----------------
__global__ void k_finstats(const double* __restrict__ st, float* __restrict__ fs, double cnt) {
  double mu = st[0] / cnt;
  double var = st[1] / cnt - mu * mu;
  if (var < 0.0) var = 0.0;
  fs[0] = (float)mu;
  fs[1] = (float)(1.0 / (sqrt(var) + (double)LN_EPS));
}

__global__ void k_norm_elu_bf16(const u16* __restrict__ a, const float* __restrict__ g,
                                const float* __restrict__ b, const float* __restrict__ fs,
                                u16* __restrict__ out, int n8, int Hmask) {
  int id = blockIdx.x * blockDim.x + threadIdx.x;
  if (id >= n8) return;
  int i8 = id * 8;
  int cb = i8 & Hmask;
  uint4 v = *(const uint4*)(a + i8);
  const u32 va[4] = {v.x, v.y, v.z, v.w};
  float mu = fs[0], inv = fs[1];
  uint4 o;
  u32* op = (u32*)&o;
#pragma unroll
  for (int w = 0; w < 4; w++) {
    float y0 = (bf2f(va[w] & 0xffffu) - mu) * inv * g[cb + 2 * w] + b[cb + 2 * w];
    float y1 = (bf2f(va[w] >> 16) - mu) * inv * g[cb + 2 * w + 1] + b[cb + 2 * w + 1];
    y0 = (y0 > 0.f) ? y0 : (__expf(y0) - 1.f);
    y1 = (y1 > 0.f) ? y1 : (__expf(y1) - 1.f);
    op[w] = (u32)f2bf(y0) | ((u32)f2bf(y1) << 16);
  }
  *(uint4*)(out + i8) = o;
}

__global__ void k_norm_f32(float* __restrict__ a, const float* __restrict__ g,
                           const float* __restrict__ b, const float* __restrict__ fs,
                           int n4, int Hmask) {
  int id = blockIdx.x * blockDim.x + threadIdx.x;
  if (id >= n4) return;
  int i4 = id * 4;
  int cb = i4 & Hmask;
  float4 v = *(const float4*)(a + i4);
  float mu = fs[0], inv = fs[1];
  float4 o;
  o.x = (v.x - mu) * inv * g[cb] + b[cb];
  o.y = (v.y - mu) * inv * g[cb + 1] + b[cb + 1];
  o.z = (v.z - mu) * inv * g[cb + 2] + b[cb + 2];
  o.w = (v.w - mu) * inv * g[cb + 3] + b[cb + 3];
  *(float4*)(a + i4) = o;
}

// ---------------- launch ----------------
extern "C" void kernel_launch(void* const* d_in, const int* in_sizes, int n_in,
                              void* d_out, int out_size, void* d_ws, size_t ws_size,
                              hipStream_t stream) {
  const float* x   = (const float*)d_in[0];
  const float* Wq1 = (const float*)d_in[1];  const float* bq1 = (const float*)d_in[2];
  const float* Wk1 = (const float*)d_in[3];  const float* bk1 = (const float*)d_in[4];
  const float* Wv1 = (const float*)d_in[5];  const float* bv1 = (const float*)d_in[6];
  const float* Ws1 = (const float*)d_in[7];  const float* bs1 = (const float*)d_in[8];
  const float* g1  = (const float*)d_in[9];  const float* be1 = (const float*)d_in[10];
  const float* Wq2 = (const float*)d_in[11]; const float* bq2 = (const float*)d_in[12];
  const float* Wk2 = (const float*)d_in[13]; const float* bk2 = (const float*)d_in[14];
  const float* Wv2 = (const float*)d_in[15]; const float* bv2 = (const float*)d_in[16];
  const float* Ws2 = (const float*)d_in[17]; const float* bs2 = (const float*)d_in[18];
  const float* g2  = (const float*)d_in[19]; const float* be2 = (const float*)d_in[20];
  const int*   ei  = (const int*)d_in[21];

  const int N = in_sizes[0] / IN_DIM;   // 50000
  const int E = in_sizes[21] / 2;       // 800000
  const int* esrc = ei;
  const int* edst = ei + E;

  // ---- workspace carve (256B aligned); deg and st adjacent for single memset
  char* w = (char*)d_ws;
  auto carve = [&](size_t bytes) { char* p = w; w += (bytes + 255) & ~(size_t)255; return p; };
  int* deg   = (int*)carve((size_t)(N + 1) * 4);
  double* st = (double*)carve(64);   // st[0..1]: layer1, st[2..3]: layer2
  u16* x_bf  = (u16*)carve((size_t)N * IN_DIM * 2);          // later reused as h1
  u16* Wt1   = (u16*)carve((size_t)4 * HID * IN_DIM * 2);
  u16* Wt2   = (u16*)carve((size_t)4 * OUTD * HID * 2);
  float* bc1 = (float*)carve(4 * HID * 4);
  float* bc2 = (float*)carve(4 * OUTD * 4);
  u16* qkvs1 = (u16*)carve((size_t)N * 4 * HID * 2);         // later reused as qkvs2
  u16* a1    = (u16*)carve((size_t)N * HID * 2);
  int* offs  = (int*)carve((size_t)(N + 1) * 4);
  int* cur   = (int*)carve((size_t)(N + 1) * 4);
  int* ssrc  = (int*)carve((size_t)E * 4);
  int* bsum  = (int*)carve(1024);
  int* boff  = (int*)carve(1024);
  float* fs  = (float*)carve(64);    // fs[0..1], fs[2..3]
  u16* h1    = x_bf;
  u16* qkvs2 = qkvs1;

  hipMemsetAsync(deg, 0, (size_t)((char*)st - (char*)deg) + 64, stream);

  // ---- fused prep ----
  int n4 = N * IN_DIM / 4;
  int prep_total = n4 + 4 * HID * IN_DIM + 4 * OUTD * HID + 4 * HID + 4 * OUTD;
  k_prep<<<(prep_total + 255) / 256, 256, 0, stream>>>(
      x, x_bf, n4, Wq1, Wk1, Wv1, Ws1, Wq2, Wk2, Wv2, Ws2, Wt1, Wt2,
      bq1, bk1, bv1, bs1, bq2, bk2, bv2, bs2, bc1, bc2);

  // ---- counting sort of edges by dst ----
  int nb = (N + 255) / 256;
  k_hist<<<(E + 255) / 256, 256, 0, stream>>>(edst, deg, E);
  k_block_sum<<<nb, 256, 0, stream>>>(deg, bsum, N);
  k_scan_bsum<<<1, 256, 0, stream>>>(bsum, boff, nb);
  k_scan_final<<<nb, 256, 0, stream>>>(deg, boff, offs, cur, N, E);
  k_scatter<<<(E + 255) / 256, 256, 0, stream>>>(esrc, edst, cur, ssrc, E);

  // ---- layer 1 ----
  dim3 gg1((N + 127) / 128, (4 * HID) / 128);
  k_gemm_bf16_nt<<<gg1, 256, 0, stream>>>(x_bf, Wt1, bc1, qkvs1, N, IN_DIM, 4 * HID);
  k_conv<HID, true><<<(N + 3) / 4, 256, 0, stream>>>(qkvs1, offs, ssrc, a1, nullptr, N,
                                                     1.0f / sqrtf((float)HID), st);
  k_finstats<<<1, 1, 0, stream>>>(st, fs, (double)N * HID);
  k_norm_elu_bf16<<<(N * HID / 8 + 255) / 256, 256, 0, stream>>>(a1, g1, be1, fs, h1,
                                                                 N * HID / 8, HID - 1);

  // ---- layer 2 ----
  dim3 gg2((N + 127) / 128, (4 * OUTD) / 128);
  k_gemm_bf16_nt<<<gg2, 256, 0, stream>>>(h1, Wt2, bc2, qkvs2, N, HID, 4 * OUTD);
  k_conv<OUTD, false><<<(N + 3) / 4, 256, 0, stream>>>(qkvs2, offs, ssrc, nullptr, (float*)d_out,
                                                       N, 1.0f / sqrtf((float)OUTD), st + 2);
  k_finstats<<<1, 1, 0, stream>>>(st + 2, fs + 2, (double)N * OUTD);
  k_norm_f32<<<(N * OUTD / 4 + 255) / 256, 256, 0, stream>>>((float*)d_out, g2, be2, fs + 2,
                                                             N * OUTD / 4, OUTD - 1);
}

// Round 4
// 739.466 us; speedup vs baseline: 1.4673x; 1.4673x over previous
//
#include <hip/hip_runtime.h>
#include <stdint.h>
#include <math.h>

#define IN_DIM 512
#define HID    256
#define OUTD   128
#define LN_EPS 1e-5f

typedef unsigned short u16;
typedef unsigned int   u32;
typedef short short8 __attribute__((ext_vector_type(8)));
typedef float f32x4  __attribute__((ext_vector_type(4)));

__device__ __forceinline__ float bf2f(u32 h) {
  union { u32 u; float f; } c; c.u = h << 16; return c.f;
}
__device__ __forceinline__ u16 f2bf(float f) {
  union { float f; u32 u; } c; c.f = f;
  u32 u = c.u;
  return (u16)((u + 0x7FFFu + ((u >> 16) & 1u)) >> 16);  // RNE
}

__device__ __forceinline__ void gload_lds16(const void* g, void* l) {
  __builtin_amdgcn_global_load_lds((const __attribute__((address_space(1))) void*)g,
                                   (__attribute__((address_space(3))) void*)l, 16, 0, 0);
}

// ---------------- fused prep: x->bf16, 8 weight transposes, 2 bias concats ----
__global__ void k_prep(const float* __restrict__ x, u16* __restrict__ x_bf, int n4,
                       const float* __restrict__ Wq1, const float* __restrict__ Wk1,
                       const float* __restrict__ Wv1, const float* __restrict__ Ws1,
                       const float* __restrict__ Wq2, const float* __restrict__ Wk2,
                       const float* __restrict__ Wv2, const float* __restrict__ Ws2,
                       u16* __restrict__ Wt1, u16* __restrict__ Wt2,
                       const float* __restrict__ bq1, const float* __restrict__ bk1,
                       const float* __restrict__ bv1, const float* __restrict__ bs1,
                       const float* __restrict__ bq2, const float* __restrict__ bk2,
                       const float* __restrict__ bv2, const float* __restrict__ bs2,
                       float* __restrict__ bc1, float* __restrict__ bc2) {
  const int W1SZ = 4 * HID * IN_DIM;   // per-mat 2^17
  const int W2SZ = 4 * OUTD * HID;     // per-mat 2^15
  int id = blockIdx.x * blockDim.x + threadIdx.x;
  if (id < n4) {
    const float4 v = ((const float4*)x)[id];
    ushort4 o;
    o.x = f2bf(v.x); o.y = f2bf(v.y); o.z = f2bf(v.z); o.w = f2bf(v.w);
    ((ushort4*)x_bf)[id] = o;
    return;
  }
  id -= n4;
  if (id < W1SZ) {  // out[mat][n*512+k] = in[k*256+n]
    int mat = id >> 17, r = id & 131071;
    int n = r >> 9, k = r & 511;
    const float* src = (mat == 0) ? Wq1 : (mat == 1) ? Wk1 : (mat == 2) ? Wv1 : Ws1;
    Wt1[id] = f2bf(src[k * HID + n]);
    return;
  }
  id -= W1SZ;
  if (id < W2SZ) {
    int mat = id >> 15, r = id & 32767;
    int n = r >> 8, k = r & 255;
    const float* src = (mat == 0) ? Wq2 : (mat == 1) ? Wk2 : (mat == 2) ? Wv2 : Ws2;
    Wt2[id] = f2bf(src[k * OUTD + n]);
    return;
  }
  id -= W2SZ;
  if (id < 4 * HID) {
    const float* s = (id < HID) ? bq1 : (id < 2 * HID) ? bk1 : (id < 3 * HID) ? bv1 : bs1;
    bc1[id] = s[id & (HID - 1)];
    return;
  }
  id -= 4 * HID;
  if (id < 4 * OUTD) {
    const float* s = (id < OUTD) ? bq2 : (id < 2 * OUTD) ? bk2 : (id < 3 * OUTD) ? bv2 : bs2;
    bc2[id] = s[id & (OUTD - 1)];
  }
}

// ---------------- edge sort (counting sort by dst) ----------------
__global__ void k_hist(const int* __restrict__ dst, int* __restrict__ deg, int E) {
  int e = blockIdx.x * blockDim.x + threadIdx.x;
  if (e < E) atomicAdd(&deg[dst[e]], 1);
}

__global__ void k_block_sum(const int* __restrict__ deg, int* __restrict__ bsum, int n) {
  __shared__ int sm[256];
  int i = blockIdx.x * 256 + threadIdx.x;
  sm[threadIdx.x] = (i < n) ? deg[i] : 0;
  __syncthreads();
  for (int off = 128; off > 0; off >>= 1) {
    if (threadIdx.x < off) sm[threadIdx.x] += sm[threadIdx.x + off];
    __syncthreads();
  }
  if (threadIdx.x == 0) bsum[blockIdx.x] = sm[0];
}

__global__ void k_scan_bsum(const int* __restrict__ bsum, int* __restrict__ boff, int nb) {
  __shared__ int sm[256];
  int t = threadIdx.x;
  int v = (t < nb) ? bsum[t] : 0;
  sm[t] = v;
  __syncthreads();
  for (int off = 1; off < 256; off <<= 1) {
    int tmp = (t >= off) ? sm[t - off] : 0;
    __syncthreads();
    sm[t] += tmp;
    __syncthreads();
  }
  if (t < nb) boff[t] = sm[t] - v;  // exclusive
}

__global__ void k_scan_final(const int* __restrict__ deg, const int* __restrict__ boff,
                             int* __restrict__ offsets, int* __restrict__ cur,
                             int n, int total) {
  __shared__ int sm[256];
  int t = threadIdx.x;
  int i = blockIdx.x * 256 + t;
  int v = (i < n) ? deg[i] : 0;
  sm[t] = v;
  __syncthreads();
  for (int off = 1; off < 256; off <<= 1) {
    int tmp = (t >= off) ? sm[t - off] : 0;
    __syncthreads();
    sm[t] += tmp;
    __syncthreads();
  }
  if (i < n) {
    int o = boff[blockIdx.x] + sm[t] - v;
    offsets[i] = o;
    cur[i] = o;
  }
  if (i == 0) offsets[n] = total;
}

__global__ void k_scatter(const int* __restrict__ src, const int* __restrict__ dst,
                          int* __restrict__ cursor, int* __restrict__ ssrc, int E) {
  int e = blockIdx.x * blockDim.x + threadIdx.x;
  if (e >= E) return;
  int d = dst[e];
  int pos = atomicAdd(&cursor[d], 1);
  ssrc[pos] = src[e];
}

// ---------------- bf16 NT GEMM (m97 structure) ----------------
__global__ __launch_bounds__(256) void k_gemm_bf16_nt(
    const u16* __restrict__ A, const u16* __restrict__ Bt, const float* __restrict__ bias,
    u16* __restrict__ C, int M, int K, int Nt) {
  __shared__ __align__(16) u16 As[128 * 32];
  __shared__ __align__(16) u16 Bs[128 * 32];
  const int tid = threadIdx.x;
  const int bm0 = blockIdx.x * 128;
  const int bn0 = blockIdx.y * 128;
  const int wave = tid >> 6, lane = tid & 63;
  const int q = lane >> 4, r16 = lane & 15;
  const int wm = (wave >> 1) * 64, wn = (wave & 1) * 64;

  f32x4 acc[4][4];
#pragma unroll
  for (int i = 0; i < 4; i++)
#pragma unroll
    for (int j = 0; j < 4; j++) acc[i][j] = (f32x4){0.f, 0.f, 0.f, 0.f};

  const int r0 = tid >> 2;
  const int c0 = (tid & 3) * 8;

  for (int kt = 0; kt < K; kt += 32) {
#pragma unroll
    for (int h = 0; h < 2; ++h) {
      int row = r0 + h * 64;
      gload_lds16(A + (size_t)(bm0 + row) * K + kt + c0, &As[row * 32 + c0]);
      gload_lds16(Bt + (size_t)(bn0 + row) * K + kt + c0, &Bs[row * 32 + c0]);
    }
    __syncthreads();
    short8 af[4], bfr[4];
#pragma unroll
    for (int i = 0; i < 4; i++) af[i] = *(const short8*)(&As[(wm + i * 16 + r16) * 32 + q * 8]);
#pragma unroll
    for (int j = 0; j < 4; j++) bfr[j] = *(const short8*)(&Bs[(wn + j * 16 + r16) * 32 + q * 8]);
#pragma unroll
    for (int i = 0; i < 4; i++)
#pragma unroll
      for (int j = 0; j < 4; j++)
        acc[i][j] = __builtin_amdgcn_mfma_f32_16x16x32_bf16(af[i], bfr[j], acc[i][j], 0, 0, 0);
    __syncthreads();
  }

#pragma unroll
  for (int i = 0; i < 4; i++) {
#pragma unroll
    for (int r = 0; r < 4; r++) {
      int grow = bm0 + wm + i * 16 + q * 4 + r;
      if (grow >= M) continue;
      size_t rbase = (size_t)grow * Nt;
#pragma unroll
      for (int j = 0; j < 4; j++) {
        int gcol = bn0 + wn + j * 16 + r16;
        float v = acc[i][j][r] + bias[gcol];
        C[rbase + gcol] = f2bf(v);
      }
    }
  }
}

// ---------------- conv: wave-per-node online softmax, 8-edge unroll -----------
// Raw-typed gather loads (uint2 for H=256, u32 for H=128) so the compiler can
// keep all 16 loads in flight before any convert/use (R3 lesson: converted
// loads + low VGPR cap serialize the gathers).
template <int VPL> struct rawv {};
template <> struct rawv<4> { uint2 v; };
template <> struct rawv<2> { u32 v; };

template <int VPL>
__device__ __forceinline__ rawv<VPL> load_raw(const u16* __restrict__ p, int lane) {
  rawv<VPL> r;
  if constexpr (VPL == 4) r.v = *(const uint2*)(p + lane * 4);
  else r.v = *(const u32*)(p + lane * 2);
  return r;
}
template <int VPL>
__device__ __forceinline__ void cvt_raw(rawv<VPL> r, float* f) {
  if constexpr (VPL == 4) {
    f[0] = bf2f(r.v.x & 0xffffu); f[1] = bf2f(r.v.x >> 16);
    f[2] = bf2f(r.v.y & 0xffffu); f[3] = bf2f(r.v.y >> 16);
  } else {
    f[0] = bf2f(r.v & 0xffffu); f[1] = bf2f(r.v >> 16);
  }
}

template <int H, bool OUT_BF16>
__global__ __launch_bounds__(256) void k_conv(
    const u16* __restrict__ qkvs, const int* __restrict__ offsets,
    const int* __restrict__ ssrc, u16* __restrict__ out_bf,
    float* __restrict__ out_f, int n, float scale) {
  constexpr int VPL = H / 64;
  int gw = (blockIdx.x * blockDim.x + threadIdx.x) >> 6;
  int lane = threadIdx.x & 63;
  if (gw >= n) return;
  const u16* base = qkvs + (size_t)gw * (4 * H);
  float qf[VPL];
  cvt_raw<VPL>(load_raw<VPL>(base, lane), qf);
  int beg = offsets[gw], end = offsets[gw + 1];
  float m = -INFINITY, l = 0.f;
  float agg[VPL];
#pragma unroll
  for (int w = 0; w < VPL; w++) agg[w] = 0.f;

  int i = beg;
  // main: 8 edges per iteration, all 16 gathers issued before first use
  for (; i + 8 <= end; i += 8) {
    const u16* kp[8];
#pragma unroll
    for (int u = 0; u < 8; u++) kp[u] = qkvs + (size_t)ssrc[i + u] * (4 * H) + H;
    rawv<VPL> kq[8], vq[8];
#pragma unroll
    for (int u = 0; u < 8; u++) kq[u] = load_raw<VPL>(kp[u], lane);
#pragma unroll
    for (int u = 0; u < 8; u++) vq[u] = load_raw<VPL>(kp[u] + H, lane);
    float d[8];
#pragma unroll
    for (int u = 0; u < 8; u++) {
      float kf[VPL];
      cvt_raw<VPL>(kq[u], kf);
      float dd = 0.f;
#pragma unroll
      for (int w = 0; w < VPL; w++) dd += qf[w] * kf[w];
      d[u] = dd;
    }
#pragma unroll
    for (int off = 32; off > 0; off >>= 1)
#pragma unroll
      for (int u = 0; u < 8; u++) d[u] += __shfl_xor(d[u], off, 64);
    float cm = -INFINITY;
#pragma unroll
    for (int u = 0; u < 8; u++) { d[u] *= scale; cm = fmaxf(cm, d[u]); }
    float nm = fmaxf(m, cm);
    float sc = __expf(m - nm);  // m=-inf first iter -> 0
    float p[8];
    float ps = 0.f;
#pragma unroll
    for (int u = 0; u < 8; u++) { p[u] = __expf(d[u] - nm); ps += p[u]; }
    m = nm;
    l = l * sc + ps;
    float vf[8][VPL];
#pragma unroll
    for (int u = 0; u < 8; u++) cvt_raw<VPL>(vq[u], vf[u]);
#pragma unroll
    for (int w = 0; w < VPL; w++) {
      float a = agg[w] * sc;
#pragma unroll
      for (int u = 0; u < 8; u++) a += p[u] * vf[u][w];
      agg[w] = a;
    }
  }
  // tail: one predicated 8-edge round
  if (i < end) {
    const u16* kp[8];
    bool act[8];
#pragma unroll
    for (int u = 0; u < 8; u++) {
      act[u] = (i + u) < end;
      kp[u] = qkvs + (size_t)ssrc[act[u] ? i + u : beg] * (4 * H) + H;
    }
    rawv<VPL> kq[8], vq[8];
#pragma unroll
    for (int u = 0; u < 8; u++) kq[u] = load_raw<VPL>(kp[u], lane);
#pragma unroll
    for (int u = 0; u < 8; u++) vq[u] = load_raw<VPL>(kp[u] + H, lane);
    float d[8];
#pragma unroll
    for (int u = 0; u < 8; u++) {
      float kf[VPL];
      cvt_raw<VPL>(kq[u], kf);
      float dd = 0.f;
#pragma unroll
      for (int w = 0; w < VPL; w++) dd += qf[w] * kf[w];
      d[u] = dd;
    }
#pragma unroll
    for (int off = 32; off > 0; off >>= 1)
#pragma unroll
      for (int u = 0; u < 8; u++) d[u] += __shfl_xor(d[u], off, 64);
    float cm = -INFINITY;
#pragma unroll
    for (int u = 0; u < 8; u++) {
      d[u] = act[u] ? d[u] * scale : -INFINITY;
      cm = fmaxf(cm, d[u]);
    }
    float nm = fmaxf(m, cm);
    float sc = __expf(m - nm);
    float p[8];
    float ps = 0.f;
#pragma unroll
    for (int u = 0; u < 8; u++) { p[u] = act[u] ? __expf(d[u] - nm) : 0.f; ps += p[u]; }
    m = nm;
    l = l * sc + ps;
    float vf[8][VPL];
#pragma unroll
    for (int u = 0; u < 8; u++) cvt_raw<VPL>(vq[u], vf[u]);
#pragma unroll
    for (int w = 0; w < VPL; w++) {
      float a = agg[w] * sc;
#pragma unroll
      for (int u = 0; u < 8; u++) a += p[u] * vf[u][w];
      agg[w] = a;
    }
  }

  float sf[VPL];
  cvt_raw<VPL>(load_raw<VPL>(base + 3 * H, lane), sf);
  float inv = (end > beg) ? 1.f / l : 0.f;
#pragma unroll
  for (int w = 0; w < VPL; w++) {
    float r = agg[w] * inv + sf[w];
    if (OUT_BF16) out_bf[(size_t)gw * H + lane * VPL + w] = f2bf(r);
    else out_f[(size_t)gw * H + lane * VPL + w] = r;
  }
}

// ---------------- graph layernorm stats (vectorized) ----------------
__global__ void k_stats_bf16(const u16* __restrict__ a, int n8, double* __restrict__ st) {
  float s = 0.f, s2 = 0.f;
  for (int i = blockIdx.x * blockDim.x + threadIdx.x; i < n8; i += gridDim.x * blockDim.x) {
    uint4 v = ((const uint4*)a)[i];
    const u32 va[4] = {v.x, v.y, v.z, v.w};
#pragma unroll
    for (int w = 0; w < 4; w++) {
      float x0 = bf2f(va[w] & 0xffffu), x1 = bf2f(va[w] >> 16);
      s += x0 + x1; s2 += x0 * x0 + x1 * x1;
    }
  }
  __shared__ float sm[256], sm2[256];
  sm[threadIdx.x] = s; sm2[threadIdx.x] = s2;
  __syncthreads();
  for (int off = 128; off > 0; off >>= 1) {
    if (threadIdx.x < off) { sm[threadIdx.x] += sm[threadIdx.x + off]; sm2[threadIdx.x] += sm2[threadIdx.x + off]; }
    __syncthreads();
  }
  if (threadIdx.x == 0) { atomicAdd(&st[0], (double)sm[0]); atomicAdd(&st[1], (double)sm2[0]); }
}

__global__ void k_stats_f32(const float* __restrict__ a, int n4, double* __restrict__ st) {
  float s = 0.f, s2 = 0.f;
  for (int i = blockIdx.x * blockDim.x + threadIdx.x; i < n4; i += gridDim.x * blockDim.x) {
    float4 v = ((const float4*)a)[i];
    s += v.x + v.y + v.z + v.w;
    s2 += v.x * v.x + v.y * v.y + v.z * v.z + v.w * v.w;
  }
  __shared__ float sm[256], sm2[256];
  sm[threadIdx.x] = s; sm2[threadIdx.x] = s2;
  __syncthreads();
  for (int off = 128; off > 0; off >>= 1) {
    if (threadIdx.x < off) { sm[threadIdx.x] += sm[threadIdx.x + off]; sm2[threadIdx.x] += sm2[threadIdx.x + off]; }
    __syncthreads();
  }
  if (threadIdx.x == 0) { atomicAdd(&st[0], (double)sm[0]); atomicAdd(&st[1], (double)sm2[0]); }
}

__global__ void k_finstats(const double* __restrict__ st, float* __restrict__ fs, double cnt) {
  double mu = st[0] / cnt;
  double var = st[1] / cnt - mu * mu;
  if (var < 0.0) var = 0.0;
  fs[0] = (float)mu;
  fs[1] = (float)(1.0 / (sqrt(var) + (double)LN_EPS));
}

__global__ void k_norm_elu_bf16(const u16* __restrict__ a, const float* __restrict__ g,
                                const float* __restrict__ b, const float* __restrict__ fs,
                                u16* __restrict__ out, int n8, int Hmask) {
  int id = blockIdx.x * blockDim.x + threadIdx.x;
  if (id >= n8) return;
  int i8 = id * 8;
  int cb = i8 & Hmask;
  uint4 v = *(const uint4*)(a + i8);
  const u32 va[4] = {v.x, v.y, v.z, v.w};
  float mu = fs[0], inv = fs[1];
  uint4 o;
  u32* op = (u32*)&o;
#pragma unroll
  for (int w = 0; w < 4; w++) {
    float y0 = (bf2f(va[w] & 0xffffu) - mu) * inv * g[cb + 2 * w] + b[cb + 2 * w];
    float y1 = (bf2f(va[w] >> 16) - mu) * inv * g[cb + 2 * w + 1] + b[cb + 2 * w + 1];
    y0 = (y0 > 0.f) ? y0 : (__expf(y0) - 1.f);
    y1 = (y1 > 0.f) ? y1 : (__expf(y1) - 1.f);
    op[w] = (u32)f2bf(y0) | ((u32)f2bf(y1) << 16);
  }
  *(uint4*)(out + i8) = o;
}

__global__ void k_norm_f32(float* __restrict__ a, const float* __restrict__ g,
                           const float* __restrict__ b, const float* __restrict__ fs,
                           int n4, int Hmask) {
  int id = blockIdx.x * blockDim.x + threadIdx.x;
  if (id >= n4) return;
  int i4 = id * 4;
  int cb = i4 & Hmask;
  float4 v = *(const float4*)(a + i4);
  float mu = fs[0], inv = fs[1];
  float4 o;
  o.x = (v.x - mu) * inv * g[cb] + b[cb];
  o.y = (v.y - mu) * inv * g[cb + 1] + b[cb + 1];
  o.z = (v.z - mu) * inv * g[cb + 2] + b[cb + 2];
  o.w = (v.w - mu) * inv * g[cb + 3] + b[cb + 3];
  *(float4*)(a + i4) = o;
}

// ---------------- launch ----------------
extern "C" void kernel_launch(void* const* d_in, const int* in_sizes, int n_in,
                              void* d_out, int out_size, void* d_ws, size_t ws_size,
                              hipStream_t stream) {
  const float* x   = (const float*)d_in[0];
  const float* Wq1 = (const float*)d_in[1];  const float* bq1 = (const float*)d_in[2];
  const float* Wk1 = (const float*)d_in[3];  const float* bk1 = (const float*)d_in[4];
  const float* Wv1 = (const float*)d_in[5];  const float* bv1 = (const float*)d_in[6];
  const float* Ws1 = (const float*)d_in[7];  const float* bs1 = (const float*)d_in[8];
  const float* g1  = (const float*)d_in[9];  const float* be1 = (const float*)d_in[10];
  const float* Wq2 = (const float*)d_in[11]; const float* bq2 = (const float*)d_in[12];
  const float* Wk2 = (const float*)d_in[13]; const float* bk2 = (const float*)d_in[14];
  const float* Wv2 = (const float*)d_in[15]; const float* bv2 = (const float*)d_in[16];
  const float* Ws2 = (const float*)d_in[17]; const float* bs2 = (const float*)d_in[18];
  const float* g2  = (const float*)d_in[19]; const float* be2 = (const float*)d_in[20];
  const int*   ei  = (const int*)d_in[21];

  const int N = in_sizes[0] / IN_DIM;   // 50000
  const int E = in_sizes[21] / 2;       // 800000
  const int* esrc = ei;
  const int* edst = ei + E;

  // ---- workspace carve (256B aligned); deg and st adjacent for single memset
  char* w = (char*)d_ws;
  auto carve = [&](size_t bytes) { char* p = w; w += (bytes + 255) & ~(size_t)255; return p; };
  int* deg   = (int*)carve((size_t)(N + 1) * 4);
  double* st = (double*)carve(64);   // st[0..1]: layer1, st[2..3]: layer2
  u16* x_bf  = (u16*)carve((size_t)N * IN_DIM * 2);          // later reused as h1
  u16* Wt1   = (u16*)carve((size_t)4 * HID * IN_DIM * 2);
  u16* Wt2   = (u16*)carve((size_t)4 * OUTD * HID * 2);
  float* bc1 = (float*)carve(4 * HID * 4);
  float* bc2 = (float*)carve(4 * OUTD * 4);
  u16* qkvs1 = (u16*)carve((size_t)N * 4 * HID * 2);         // later reused as qkvs2
  u16* a1    = (u16*)carve((size_t)N * HID * 2);
  int* offs  = (int*)carve((size_t)(N + 1) * 4);
  int* cur   = (int*)carve((size_t)(N + 1) * 4);
  int* ssrc  = (int*)carve((size_t)E * 4);
  int* bsum  = (int*)carve(1024);
  int* boff  = (int*)carve(1024);
  float* fs  = (float*)carve(64);    // fs[0..1], fs[2..3]
  u16* h1    = x_bf;
  u16* qkvs2 = qkvs1;

  hipMemsetAsync(deg, 0, (size_t)((char*)st - (char*)deg) + 64, stream);

  // ---- fused prep ----
  int n4 = N * IN_DIM / 4;
  int prep_total = n4 + 4 * HID * IN_DIM + 4 * OUTD * HID + 4 * HID + 4 * OUTD;
  k_prep<<<(prep_total + 255) / 256, 256, 0, stream>>>(
      x, x_bf, n4, Wq1, Wk1, Wv1, Ws1, Wq2, Wk2, Wv2, Ws2, Wt1, Wt2,
      bq1, bk1, bv1, bs1, bq2, bk2, bv2, bs2, bc1, bc2);

  // ---- counting sort of edges by dst ----
  int nb = (N + 255) / 256;
  k_hist<<<(E + 255) / 256, 256, 0, stream>>>(edst, deg, E);
  k_block_sum<<<nb, 256, 0, stream>>>(deg, bsum, N);
  k_scan_bsum<<<1, 256, 0, stream>>>(bsum, boff, nb);
  k_scan_final<<<nb, 256, 0, stream>>>(deg, boff, offs, cur, N, E);
  k_scatter<<<(E + 255) / 256, 256, 0, stream>>>(esrc, edst, cur, ssrc, E);

  // ---- layer 1 ----
  dim3 gg1((N + 127) / 128, (4 * HID) / 128);
  k_gemm_bf16_nt<<<gg1, 256, 0, stream>>>(x_bf, Wt1, bc1, qkvs1, N, IN_DIM, 4 * HID);
  k_conv<HID, true><<<(N + 3) / 4, 256, 0, stream>>>(qkvs1, offs, ssrc, a1, nullptr, N,
                                                     1.0f / sqrtf((float)HID));
  k_stats_bf16<<<2048, 256, 0, stream>>>(a1, N * HID / 8, st);
  k_finstats<<<1, 1, 0, stream>>>(st, fs, (double)N * HID);
  k_norm_elu_bf16<<<(N * HID / 8 + 255) / 256, 256, 0, stream>>>(a1, g1, be1, fs, h1,
                                                                 N * HID / 8, HID - 1);

  // ---- layer 2 ----
  dim3 gg2((N + 127) / 128, (4 * OUTD) / 128);
  k_gemm_bf16_nt<<<gg2, 256, 0, stream>>>(h1, Wt2, bc2, qkvs2, N, HID, 4 * OUTD);
  k_conv<OUTD, false><<<(N + 3) / 4, 256, 0, stream>>>(qkvs2, offs, ssrc, nullptr, (float*)d_out,
                                                       N, 1.0f / sqrtf((float)OUTD));
  k_stats_f32<<<2048, 256, 0, stream>>>((const float*)d_out, N * OUTD / 4, st + 2);
  k_finstats<<<1, 1, 0, stream>>>(st + 2, fs + 2, (double)N * OUTD);
  k_norm_f32<<<(N * OUTD / 4 + 255) / 256, 256, 0, stream>>>((float*)d_out, g2, be2, fs + 2,
                                                             N * OUTD / 4, OUTD - 1);
}

// Round 5
// 734.074 us; speedup vs baseline: 1.4781x; 1.0073x over previous
//
#include <hip/hip_runtime.h>
#include <stdint.h>
#include <math.h>

#define IN_DIM 512
#define HID    256
#define OUTD   128
#define LN_EPS 1e-5f

typedef unsigned short u16;
typedef unsigned int   u32;
typedef short short8 __attribute__((ext_vector_type(8)));
typedef float f32x4  __attribute__((ext_vector_type(4)));

__device__ __forceinline__ float bf2f(u32 h) {
  union { u32 u; float f; } c; c.u = h << 16; return c.f;
}
__device__ __forceinline__ u16 f2bf(float f) {
  union { float f; u32 u; } c; c.f = f;
  u32 u = c.u;
  return (u16)((u + 0x7FFFu + ((u >> 16) & 1u)) >> 16);  // RNE
}

__device__ __forceinline__ void gload_lds16(const void* g, void* l) {
  __builtin_amdgcn_global_load_lds((const __attribute__((address_space(1))) void*)g,
                                   (__attribute__((address_space(3))) void*)l, 16, 0, 0);
}

// ---------------- prep: x->bf16 (coalesced) + bias concats ----------------
__global__ void k_prep(const float* __restrict__ x, u16* __restrict__ x_bf, int n4,
                       const float* __restrict__ bq1, const float* __restrict__ bk1,
                       const float* __restrict__ bv1, const float* __restrict__ bs1,
                       const float* __restrict__ bq2, const float* __restrict__ bk2,
                       const float* __restrict__ bv2, const float* __restrict__ bs2,
                       float* __restrict__ bc1, float* __restrict__ bc2) {
  int id = blockIdx.x * blockDim.x + threadIdx.x;
  if (id < n4) {
    const float4 v = ((const float4*)x)[id];
    ushort4 o;
    o.x = f2bf(v.x); o.y = f2bf(v.y); o.z = f2bf(v.z); o.w = f2bf(v.w);
    ((ushort4*)x_bf)[id] = o;
    return;
  }
  id -= n4;
  if (id < 4 * HID) {
    const float* s = (id < HID) ? bq1 : (id < 2 * HID) ? bk1 : (id < 3 * HID) ? bv1 : bs1;
    bc1[id] = s[id & (HID - 1)];
    return;
  }
  id -= 4 * HID;
  if (id < 4 * OUTD) {
    const float* s = (id < OUTD) ? bq2 : (id < 2 * OUTD) ? bk2 : (id < 3 * OUTD) ? bv2 : bs2;
    bc2[id] = s[id & (OUTD - 1)];
  }
}

// ---------------- LDS-tiled weight transpose (both sides coalesced) ----------
// in: [K][Nw] fp32 row-major (4 mats), out: [mat][Nw][K] bf16 row-major.
// 32x32 tiles, block (32,8). LDS stride 33 u16 -> <=2-way bank alias (free).
__global__ void k_transpose4(const float* __restrict__ s0, const float* __restrict__ s1,
                             const float* __restrict__ s2, const float* __restrict__ s3,
                             u16* __restrict__ out, int K, int Nw) {
  __shared__ u16 t[32][33];
  const float* src = (blockIdx.z == 0) ? s0 : (blockIdx.z == 1) ? s1
                     : (blockIdx.z == 2) ? s2 : s3;
  u16* dst = out + (size_t)blockIdx.z * K * Nw;
  int k0 = blockIdx.x * 32, n0 = blockIdx.y * 32;
  int tx = threadIdx.x, ty = threadIdx.y;
#pragma unroll
  for (int i = 0; i < 32; i += 8)  // read coalesced in n
    t[ty + i][tx] = f2bf(src[(size_t)(k0 + ty + i) * Nw + n0 + tx]);
  __syncthreads();
#pragma unroll
  for (int i = 0; i < 32; i += 8)  // write coalesced in k
    dst[(size_t)(n0 + ty + i) * K + k0 + tx] = t[tx][ty + i];
}

// ---------------- edge sort (counting sort by dst) ----------------
__global__ void k_hist(const int* __restrict__ dst, int* __restrict__ deg, int E) {
  int e = blockIdx.x * blockDim.x + threadIdx.x;
  if (e < E) atomicAdd(&deg[dst[e]], 1);
}

__global__ void k_block_sum(const int* __restrict__ deg, int* __restrict__ bsum, int n) {
  __shared__ int sm[256];
  int i = blockIdx.x * 256 + threadIdx.x;
  sm[threadIdx.x] = (i < n) ? deg[i] : 0;
  __syncthreads();
  for (int off = 128; off > 0; off >>= 1) {
    if (threadIdx.x < off) sm[threadIdx.x] += sm[threadIdx.x + off];
    __syncthreads();
  }
  if (threadIdx.x == 0) bsum[blockIdx.x] = sm[0];
}

__global__ void k_scan_bsum(const int* __restrict__ bsum, int* __restrict__ boff, int nb) {
  __shared__ int sm[256];
  int t = threadIdx.x;
  int v = (t < nb) ? bsum[t] : 0;
  sm[t] = v;
  __syncthreads();
  for (int off = 1; off < 256; off <<= 1) {
    int tmp = (t >= off) ? sm[t - off] : 0;
    __syncthreads();
    sm[t] += tmp;
    __syncthreads();
  }
  if (t < nb) boff[t] = sm[t] - v;  // exclusive
}

__global__ void k_scan_final(const int* __restrict__ deg, const int* __restrict__ boff,
                             int* __restrict__ offsets, int* __restrict__ cur,
                             int n, int total) {
  __shared__ int sm[256];
  int t = threadIdx.x;
  int i = blockIdx.x * 256 + t;
  int v = (i < n) ? deg[i] : 0;
  sm[t] = v;
  __syncthreads();
  for (int off = 1; off < 256; off <<= 1) {
    int tmp = (t >= off) ? sm[t - off] : 0;
    __syncthreads();
    sm[t] += tmp;
    __syncthreads();
  }
  if (i < n) {
    int o = boff[blockIdx.x] + sm[t] - v;
    offsets[i] = o;
    cur[i] = o;
  }
  if (i == 0) offsets[n] = total;
}

__global__ void k_scatter(const int* __restrict__ src, const int* __restrict__ dst,
                          int* __restrict__ cursor, int* __restrict__ ssrc, int E) {
  int e = blockIdx.x * blockDim.x + threadIdx.x;
  if (e >= E) return;
  int d = dst[e];
  int pos = atomicAdd(&cursor[d], 1);
  ssrc[pos] = src[e];
}

// ---------------- bf16 NT GEMM (m97 structure) ----------------
__global__ __launch_bounds__(256) void k_gemm_bf16_nt(
    const u16* __restrict__ A, const u16* __restrict__ Bt, const float* __restrict__ bias,
    u16* __restrict__ C, int M, int K, int Nt) {
  __shared__ __align__(16) u16 As[128 * 32];
  __shared__ __align__(16) u16 Bs[128 * 32];
  const int tid = threadIdx.x;
  const int bm0 = blockIdx.x * 128;
  const int bn0 = blockIdx.y * 128;
  const int wave = tid >> 6, lane = tid & 63;
  const int q = lane >> 4, r16 = lane & 15;
  const int wm = (wave >> 1) * 64, wn = (wave & 1) * 64;

  f32x4 acc[4][4];
#pragma unroll
  for (int i = 0; i < 4; i++)
#pragma unroll
    for (int j = 0; j < 4; j++) acc[i][j] = (f32x4){0.f, 0.f, 0.f, 0.f};

  const int r0 = tid >> 2;
  const int c0 = (tid & 3) * 8;

  for (int kt = 0; kt < K; kt += 32) {
#pragma unroll
    for (int h = 0; h < 2; ++h) {
      int row = r0 + h * 64;
      gload_lds16(A + (size_t)(bm0 + row) * K + kt + c0, &As[row * 32 + c0]);
      gload_lds16(Bt + (size_t)(bn0 + row) * K + kt + c0, &Bs[row * 32 + c0]);
    }
    __syncthreads();
    short8 af[4], bfr[4];
#pragma unroll
    for (int i = 0; i < 4; i++) af[i] = *(const short8*)(&As[(wm + i * 16 + r16) * 32 + q * 8]);
#pragma unroll
    for (int j = 0; j < 4; j++) bfr[j] = *(const short8*)(&Bs[(wn + j * 16 + r16) * 32 + q * 8]);
#pragma unroll
    for (int i = 0; i < 4; i++)
#pragma unroll
      for (int j = 0; j < 4; j++)
        acc[i][j] = __builtin_amdgcn_mfma_f32_16x16x32_bf16(af[i], bfr[j], acc[i][j], 0, 0, 0);
    __syncthreads();
  }

#pragma unroll
  for (int i = 0; i < 4; i++) {
#pragma unroll
    for (int r = 0; r < 4; r++) {
      int grow = bm0 + wm + i * 16 + q * 4 + r;
      if (grow >= M) continue;
      size_t rbase = (size_t)grow * Nt;
#pragma unroll
      for (int j = 0; j < 4; j++) {
        int gcol = bn0 + wn + j * 16 + r16;
        float v = acc[i][j][r] + bias[gcol];
        C[rbase + gcol] = f2bf(v);
      }
    }
  }
}

// ---------------- conv: wave-per-node online softmax, 4-edge unroll (R2) -----
template <int VPL>
__device__ __forceinline__ void load_bf(const u16* __restrict__ p, int lane, float* f) {
  if constexpr (VPL == 4) {
    uint2 r = *(const uint2*)(p + lane * 4);
    f[0] = bf2f(r.x & 0xffffu); f[1] = bf2f(r.x >> 16);
    f[2] = bf2f(r.y & 0xffffu); f[3] = bf2f(r.y >> 16);
  } else {
    u32 r = *(const u32*)(p + lane * 2);
    f[0] = bf2f(r & 0xffffu); f[1] = bf2f(r >> 16);
  }
}

template <int H, bool OUT_BF16>
__global__ __launch_bounds__(256) void k_conv(
    const u16* __restrict__ qkvs, const int* __restrict__ offsets,
    const int* __restrict__ ssrc, u16* __restrict__ out_bf,
    float* __restrict__ out_f, int n, float scale) {
  constexpr int VPL = H / 64;
  int gw = (blockIdx.x * blockDim.x + threadIdx.x) >> 6;
  int lane = threadIdx.x & 63;
  if (gw >= n) return;
  const u16* base = qkvs + (size_t)gw * (4 * H);
  float qf[VPL];
  load_bf<VPL>(base, lane, qf);
  int beg = offsets[gw], end = offsets[gw + 1];
  float m = -INFINITY, l = 0.f;
  float agg[VPL];
#pragma unroll
  for (int w = 0; w < VPL; w++) agg[w] = 0.f;

  int i = beg;
  for (; i + 4 <= end; i += 4) {
    int s0 = ssrc[i], s1 = ssrc[i + 1], s2 = ssrc[i + 2], s3 = ssrc[i + 3];
    const u16* k0p = qkvs + (size_t)s0 * (4 * H) + H;
    const u16* k1p = qkvs + (size_t)s1 * (4 * H) + H;
    const u16* k2p = qkvs + (size_t)s2 * (4 * H) + H;
    const u16* k3p = qkvs + (size_t)s3 * (4 * H) + H;
    float k0[VPL], k1[VPL], k2[VPL], k3[VPL];
    float v0[VPL], v1[VPL], v2[VPL], v3[VPL];
    load_bf<VPL>(k0p, lane, k0);
    load_bf<VPL>(k1p, lane, k1);
    load_bf<VPL>(k2p, lane, k2);
    load_bf<VPL>(k3p, lane, k3);
    load_bf<VPL>(k0p + H, lane, v0);
    load_bf<VPL>(k1p + H, lane, v1);
    load_bf<VPL>(k2p + H, lane, v2);
    load_bf<VPL>(k3p + H, lane, v3);
    float d0 = 0.f, d1 = 0.f, d2 = 0.f, d3 = 0.f;
#pragma unroll
    for (int w = 0; w < VPL; w++) {
      d0 += qf[w] * k0[w]; d1 += qf[w] * k1[w];
      d2 += qf[w] * k2[w]; d3 += qf[w] * k3[w];
    }
#pragma unroll
    for (int off = 32; off > 0; off >>= 1) {
      d0 += __shfl_xor(d0, off, 64);
      d1 += __shfl_xor(d1, off, 64);
      d2 += __shfl_xor(d2, off, 64);
      d3 += __shfl_xor(d3, off, 64);
    }
    d0 *= scale; d1 *= scale; d2 *= scale; d3 *= scale;
    float cm = fmaxf(fmaxf(d0, d1), fmaxf(d2, d3));
    float nm = fmaxf(m, cm);
    float sc = __expf(m - nm);  // m=-inf first round -> 0
    float p0 = __expf(d0 - nm), p1 = __expf(d1 - nm);
    float p2 = __expf(d2 - nm), p3 = __expf(d3 - nm);
    m = nm;
    l = l * sc + (p0 + p1) + (p2 + p3);
#pragma unroll
    for (int w = 0; w < VPL; w++)
      agg[w] = agg[w] * sc + p0 * v0[w] + p1 * v1[w] + p2 * v2[w] + p3 * v3[w];
  }
  for (; i < end; ++i) {
    int s = ssrc[i];
    const u16* kb = qkvs + (size_t)s * (4 * H) + H;
    float kf[VPL], vf[VPL];
    load_bf<VPL>(kb, lane, kf);
    load_bf<VPL>(kb + H, lane, vf);
    float d = 0.f;
#pragma unroll
    for (int w = 0; w < VPL; w++) d += qf[w] * kf[w];
#pragma unroll
    for (int off = 32; off > 0; off >>= 1) d += __shfl_xor(d, off, 64);
    float score = d * scale;
    float nm = fmaxf(m, score);
    float sc = __expf(m - nm);
    float p = __expf(score - nm);
    m = nm;
    l = l * sc + p;
#pragma unroll
    for (int w = 0; w < VPL; w++) agg[w] = agg[w] * sc + p * vf[w];
  }

  float sf[VPL];
  load_bf<VPL>(base + 3 * H, lane, sf);
  float inv = (end > beg) ? 1.f / l : 0.f;
#pragma unroll
  for (int w = 0; w < VPL; w++) {
    float r = agg[w] * inv + sf[w];
    if (OUT_BF16) out_bf[(size_t)gw * H + lane * VPL + w] = f2bf(r);
    else out_f[(size_t)gw * H + lane * VPL + w] = r;
  }
}

// ---------------- graph layernorm stats (vectorized) ----------------
__global__ void k_stats_bf16(const u16* __restrict__ a, int n8, double* __restrict__ st) {
  float s = 0.f, s2 = 0.f;
  for (int i = blockIdx.x * blockDim.x + threadIdx.x; i < n8; i += gridDim.x * blockDim.x) {
    uint4 v = ((const uint4*)a)[i];
    const u32 va[4] = {v.x, v.y, v.z, v.w};
#pragma unroll
    for (int w = 0; w < 4; w++) {
      float x0 = bf2f(va[w] & 0xffffu), x1 = bf2f(va[w] >> 16);
      s += x0 + x1; s2 += x0 * x0 + x1 * x1;
    }
  }
  __shared__ float sm[256], sm2[256];
  sm[threadIdx.x] = s; sm2[threadIdx.x] = s2;
  __syncthreads();
  for (int off = 128; off > 0; off >>= 1) {
    if (threadIdx.x < off) { sm[threadIdx.x] += sm[threadIdx.x + off]; sm2[threadIdx.x] += sm2[threadIdx.x + off]; }
    __syncthreads();
  }
  if (threadIdx.x == 0) { atomicAdd(&st[0], (double)sm[0]); atomicAdd(&st[1], (double)sm2[0]); }
}

__global__ void k_stats_f32(const float* __restrict__ a, int n4, double* __restrict__ st) {
  float s = 0.f, s2 = 0.f;
  for (int i = blockIdx.x * blockDim.x + threadIdx.x; i < n4; i += gridDim.x * blockDim.x) {
    float4 v = ((const float4*)a)[i];
    s += v.x + v.y + v.z + v.w;
    s2 += v.x * v.x + v.y * v.y + v.z * v.z + v.w * v.w;
  }
  __shared__ float sm[256], sm2[256];
  sm[threadIdx.x] = s; sm2[threadIdx.x] = s2;
  __syncthreads();
  for (int off = 128; off > 0; off >>= 1) {
    if (threadIdx.x < off) { sm[threadIdx.x] += sm[threadIdx.x + off]; sm2[threadIdx.x] += sm2[threadIdx.x + off]; }
    __syncthreads();
  }
  if (threadIdx.x == 0) { atomicAdd(&st[0], (double)sm[0]); atomicAdd(&st[1], (double)sm2[0]); }
}

__global__ void k_finstats(const double* __restrict__ st, float* __restrict__ fs, double cnt) {
  double mu = st[0] / cnt;
  double var = st[1] / cnt - mu * mu;
  if (var < 0.0) var = 0.0;
  fs[0] = (float)mu;
  fs[1] = (float)(1.0 / (sqrt(var) + (double)LN_EPS));
}

__global__ void k_norm_elu_bf16(const u16* __restrict__ a, const float* __restrict__ g,
                                const float* __restrict__ b, const float* __restrict__ fs,
                                u16* __restrict__ out, int n8, int Hmask) {
  int id = blockIdx.x * blockDim.x + threadIdx.x;
  if (id >= n8) return;
  int i8 = id * 8;
  int cb = i8 & Hmask;
  uint4 v = *(const uint4*)(a + i8);
  const u32 va[4] = {v.x, v.y, v.z, v.w};
  float mu = fs[0], inv = fs[1];
  uint4 o;
  u32* op = (u32*)&o;
#pragma unroll
  for (int w = 0; w < 4; w++) {
    float y0 = (bf2f(va[w] & 0xffffu) - mu) * inv * g[cb + 2 * w] + b[cb + 2 * w];
    float y1 = (bf2f(va[w] >> 16) - mu) * inv * g[cb + 2 * w + 1] + b[cb + 2 * w + 1];
    y0 = (y0 > 0.f) ? y0 : (__expf(y0) - 1.f);
    y1 = (y1 > 0.f) ? y1 : (__expf(y1) - 1.f);
    op[w] = (u32)f2bf(y0) | ((u32)f2bf(y1) << 16);
  }
  *(uint4*)(out + i8) = o;
}

__global__ void k_norm_f32(float* __restrict__ a, const float* __restrict__ g,
                           const float* __restrict__ b, const float* __restrict__ fs,
                           int n4, int Hmask) {
  int id = blockIdx.x * blockDim.x + threadIdx.x;
  if (id >= n4) return;
  int i4 = id * 4;
  int cb = i4 & Hmask;
  float4 v = *(const float4*)(a + i4);
  float mu = fs[0], inv = fs[1];
  float4 o;
  o.x = (v.x - mu) * inv * g[cb] + b[cb];
  o.y = (v.y - mu) * inv * g[cb + 1] + b[cb + 1];
  o.z = (v.z - mu) * inv * g[cb + 2] + b[cb + 2];
  o.w = (v.w - mu) * inv * g[cb + 3] + b[cb + 3];
  *(float4*)(a + i4) = o;
}

// ---------------- launch ----------------
extern "C" void kernel_launch(void* const* d_in, const int* in_sizes, int n_in,
                              void* d_out, int out_size, void* d_ws, size_t ws_size,
                              hipStream_t stream) {
  const float* x   = (const float*)d_in[0];
  const float* Wq1 = (const float*)d_in[1];  const float* bq1 = (const float*)d_in[2];
  const float* Wk1 = (const float*)d_in[3];  const float* bk1 = (const float*)d_in[4];
  const float* Wv1 = (const float*)d_in[5];  const float* bv1 = (const float*)d_in[6];
  const float* Ws1 = (const float*)d_in[7];  const float* bs1 = (const float*)d_in[8];
  const float* g1  = (const float*)d_in[9];  const float* be1 = (const float*)d_in[10];
  const float* Wq2 = (const float*)d_in[11]; const float* bq2 = (const float*)d_in[12];
  const float* Wk2 = (const float*)d_in[13]; const float* bk2 = (const float*)d_in[14];
  const float* Wv2 = (const float*)d_in[15]; const float* bv2 = (const float*)d_in[16];
  const float* Ws2 = (const float*)d_in[17]; const float* bs2 = (const float*)d_in[18];
  const float* g2  = (const float*)d_in[19]; const float* be2 = (const float*)d_in[20];
  const int*   ei  = (const int*)d_in[21];

  const int N = in_sizes[0] / IN_DIM;   // 50000
  const int E = in_sizes[21] / 2;       // 800000
  const int* esrc = ei;
  const int* edst = ei + E;

  // ---- workspace carve (256B aligned); deg and st adjacent for single memset
  char* w = (char*)d_ws;
  auto carve = [&](size_t bytes) { char* p = w; w += (bytes + 255) & ~(size_t)255; return p; };
  int* deg   = (int*)carve((size_t)(N + 1) * 4);
  double* st = (double*)carve(64);   // st[0..1]: layer1, st[2..3]: layer2
  u16* x_bf  = (u16*)carve((size_t)N * IN_DIM * 2);          // later reused as h1
  u16* Wt1   = (u16*)carve((size_t)4 * HID * IN_DIM * 2);
  u16* Wt2   = (u16*)carve((size_t)4 * OUTD * HID * 2);
  float* bc1 = (float*)carve(4 * HID * 4);
  float* bc2 = (float*)carve(4 * OUTD * 4);
  u16* qkvs1 = (u16*)carve((size_t)N * 4 * HID * 2);         // later reused as qkvs2
  u16* a1    = (u16*)carve((size_t)N * HID * 2);
  int* offs  = (int*)carve((size_t)(N + 1) * 4);
  int* cur   = (int*)carve((size_t)(N + 1) * 4);
  int* ssrc  = (int*)carve((size_t)E * 4);
  int* bsum  = (int*)carve(1024);
  int* boff  = (int*)carve(1024);
  float* fs  = (float*)carve(64);    // fs[0..1], fs[2..3]
  u16* h1    = x_bf;
  u16* qkvs2 = qkvs1;

  hipMemsetAsync(deg, 0, (size_t)((char*)st - (char*)deg) + 64, stream);

  // ---- prep: cvt + biases; LDS-tiled transposes ----
  int n4 = N * IN_DIM / 4;
  int prep_total = n4 + 4 * HID + 4 * OUTD;
  k_prep<<<(prep_total + 255) / 256, 256, 0, stream>>>(
      x, x_bf, n4, bq1, bk1, bv1, bs1, bq2, bk2, bv2, bs2, bc1, bc2);
  dim3 tb(32, 8);
  dim3 tg1(IN_DIM / 32, HID / 32, 4);
  k_transpose4<<<tg1, tb, 0, stream>>>(Wq1, Wk1, Wv1, Ws1, Wt1, IN_DIM, HID);
  dim3 tg2(HID / 32, OUTD / 32, 4);
  k_transpose4<<<tg2, tb, 0, stream>>>(Wq2, Wk2, Wv2, Ws2, Wt2, HID, OUTD);

  // ---- counting sort of edges by dst ----
  int nb = (N + 255) / 256;
  k_hist<<<(E + 255) / 256, 256, 0, stream>>>(edst, deg, E);
  k_block_sum<<<nb, 256, 0, stream>>>(deg, bsum, N);
  k_scan_bsum<<<1, 256, 0, stream>>>(bsum, boff, nb);
  k_scan_final<<<nb, 256, 0, stream>>>(deg, boff, offs, cur, N, E);
  k_scatter<<<(E + 255) / 256, 256, 0, stream>>>(esrc, edst, cur, ssrc, E);

  // ---- layer 1 ----
  dim3 gg1((N + 127) / 128, (4 * HID) / 128);
  k_gemm_bf16_nt<<<gg1, 256, 0, stream>>>(x_bf, Wt1, bc1, qkvs1, N, IN_DIM, 4 * HID);
  k_conv<HID, true><<<(N + 3) / 4, 256, 0, stream>>>(qkvs1, offs, ssrc, a1, nullptr, N,
                                                     1.0f / sqrtf((float)HID));
  k_stats_bf16<<<2048, 256, 0, stream>>>(a1, N * HID / 8, st);
  k_finstats<<<1, 1, 0, stream>>>(st, fs, (double)N * HID);
  k_norm_elu_bf16<<<(N * HID / 8 + 255) / 256, 256, 0, stream>>>(a1, g1, be1, fs, h1,
                                                                 N * HID / 8, HID - 1);

  // ---- layer 2 ----
  dim3 gg2((N + 127) / 128, (4 * OUTD) / 128);
  k_gemm_bf16_nt<<<gg2, 256, 0, stream>>>(h1, Wt2, bc2, qkvs2, N, HID, 4 * OUTD);
  k_conv<OUTD, false><<<(N + 3) / 4, 256, 0, stream>>>(qkvs2, offs, ssrc, nullptr, (float*)d_out,
                                                       N, 1.0f / sqrtf((float)OUTD));
  k_stats_f32<<<2048, 256, 0, stream>>>((const float*)d_out, N * OUTD / 4, st + 2);
  k_finstats<<<1, 1, 0, stream>>>(st + 2, fs + 2, (double)N * OUTD);
  k_norm_f32<<<(N * OUTD / 4 + 255) / 256, 256, 0, stream>>>((float*)d_out, g2, be2, fs + 2,
                                                             N * OUTD / 4, OUTD - 1);
}